// Round 4
// baseline (154.365 us; speedup 1.0000x reference)
//
#include <hip/hip_runtime.h>
#include <hip/hip_bf16.h>
#include <hip/hip_fp16.h>
#include <math.h>

#define NUM_H 8
#define DK    64
#define DM    512
#define SEQ   2048
#define NB    2
#define MROWS (NB*SEQ)   // 4096
#define NZ    4          // attn split-K factor

typedef unsigned short u16;
typedef unsigned int   u32;
typedef __attribute__((ext_vector_type(8))) __bf16 bf16x8;
typedef __attribute__((ext_vector_type(4))) short  s16x4;
typedef __attribute__((ext_vector_type(4))) float  f32x4;

// Native RNE cast (compiler emits v_cvt_pk_bf16_f32 for pairs).
__device__ __forceinline__ u16 f2bf(float v) {
    union { __bf16 h; u16 u; } x; x.h = (__bf16)v; return x.u;
}
__device__ __forceinline__ u16 f2h(float v) {
    union { _Float16 h; u16 u; } x; x.h = (_Float16)v; return x.u;
}
__device__ __forceinline__ bf16x8 ld_bf8(const u16* p) {
    union { uint4 u; bf16x8 v; } t;
    t.u = *(const uint4*)p;
    return t.v;
}
__device__ __forceinline__ uint4 pack8bf(const float* f) {
    uint4 o;
    o.x = (u32)f2bf(f[0]) | ((u32)f2bf(f[1]) << 16);
    o.y = (u32)f2bf(f[2]) | ((u32)f2bf(f[3]) << 16);
    o.z = (u32)f2bf(f[4]) | ((u32)f2bf(f[5]) << 16);
    o.w = (u32)f2bf(f[6]) | ((u32)f2bf(f[7]) << 16);
    return o;
}
// exp2 that maps straight to v_exp_f32 (no hidden *log2e mul).
__device__ __forceinline__ float fexp2(float x) {
#if defined(__has_builtin) && __has_builtin(__builtin_amdgcn_exp2f)
    return __builtin_amdgcn_exp2f(x);
#else
    return exp2f(x);
#endif
}

// K=16 bf16 MFMA (A/B: 4 bf16 in 2 VGPR). Used for PV so the swapped-QK^T
// score layout (lane holds k = nt2*16 + quad*4 + r) feeds MFMA A directly.
__device__ __forceinline__ f32x4 mfma16bf(s16x4 a, s16x4 b, f32x4 c) {
#if defined(__has_builtin) && __has_builtin(__builtin_amdgcn_mfma_f32_16x16x16bf16_1k)
    return __builtin_amdgcn_mfma_f32_16x16x16bf16_1k(a, b, c, 0, 0, 0);
#else
    asm("v_mfma_f32_16x16x16_bf16 %0, %1, %2, %0" : "+v"(c) : "v"(a), "v"(b));
    return c;
#endif
}

// r16: one conversion pass for everything fp32 -> bf16.
// z 0..3: Wq,Wk,Wv,Wo (512x512 = 128 blocks each); z 4..6: q,k,v inputs
// (4096x512 = 1024 blocks each). grid (1024, 7) x 256.
__global__ __launch_bounds__(256) void convAll(
    const float* __restrict__ Wq, const float* __restrict__ Wk,
    const float* __restrict__ Wv, const float* __restrict__ Wo,
    const float* __restrict__ xq, const float* __restrict__ xk,
    const float* __restrict__ xv,
    u16* __restrict__ Wscr, u16* __restrict__ Xb)
{
    const int z = blockIdx.y;
    const float* src;
    u16* dst;
    if (z < 4) {
        if (blockIdx.x >= 128) return;
        src = (z == 0) ? Wq : (z == 1) ? Wk : (z == 2) ? Wv : Wo;
        dst = Wscr + (size_t)z * 262144;
    } else {
        src = (z == 4) ? xq : (z == 5) ? xk : xv;
        dst = Xb + (size_t)(z - 4) * 2097152;
    }
    int i = (blockIdx.x * 256 + threadIdx.x) * 8;
    float4 a = *(const float4*)(src + i);
    float4 b = *(const float4*)(src + i + 4);
    float f[8] = {a.x, a.y, a.z, a.w, b.x, b.y, b.z, b.w};
    *(uint4*)&dst[i] = pack8bf(f);
}

// ---------------- MFMA GEMM core: OUT = X @ W^T + bias (W bf16) ----------------
// BM=64, BN=64, BK=64. 256 thr / 4 waves (2x2, 32x32 out each). LDS stride
// 72 u16 (144B, 16B-aligned).
// r16: X is ALWAYS bf16 (converted once by convAll) — A-staging is a raw
// uint4 copy. T14 async-stage (r14-proven on attn): prologue reg-load,
// ds_write -> barrier -> issue next tile's global loads -> MFMA -> barrier.
// MODE_FIN fuses the combine: sums NZ fp16 O-partials (v_pk_add_f16) and
// normalizes by 64/sum(l); the scale factors are hoisted to the prologue
// (fully unrolled => static indexing, rule #20) so the K-loop has no serial
// scalar loads. K-loop #pragma unroll keeps scr[h] compile-time-indexed.
#define MODE_QK 0
#define MODE_VT 1
#define MODE_FIN 2

template<int MODE>
__device__ __forceinline__ void gemm_core(
    const u16* __restrict__ Xb, const u16* __restrict__ Wb,
    const float* __restrict__ bias, const float* __restrict__ ClP,
    void* __restrict__ outv,
    u16* As, u16* Bs, int row0, int col0)
{
    const int tid = threadIdx.x;
    const int lane = tid & 63, w = tid >> 6;
    const int ln15 = lane & 15, quad = lane >> 4;
    const int wm = (w >> 1) * 32, wn = (w & 1) * 32;
    const int sr = tid >> 3;          // staging row 0..31 (+32 for 2nd half)
    const int scl = (tid & 7) * 8;    // staging col

    // staging base pointers (col advances by kt)
    const u16* a0p = Xb + (size_t)(row0 + sr) * DM + scl;
    const u16* a1p = Xb + (size_t)(row0 + 32 + sr) * DM + scl;
    const u16* b0p = Wb + (size_t)(col0 + sr) * DM + scl;
    const u16* b1p = Wb + (size_t)(col0 + 32 + sr) * DM + scl;

    // FIN: hoisted per-row per-head combine scales (static-indexed)
    float scr0[8], scr1[8];
    if (MODE == MODE_FIN) {
        int m0 = row0 + sr, m1 = m0 + 32;
        int cb0 = (m0 >> 11) * NUM_H, cs0 = m0 & (SEQ - 1);
        int cb1 = (m1 >> 11) * NUM_H, cs1 = m1 & (SEQ - 1);
#pragma unroll
        for (int hh = 0; hh < 8; ++hh) {
            float l0 = 0.f, l1 = 0.f;
#pragma unroll
            for (int zz = 0; zz < NZ; ++zz) {
                l0 += ClP[zz * 32768 + (cb0 + hh) * SEQ + cs0];
                l1 += ClP[zz * 32768 + (cb1 + hh) * SEQ + cs1];
            }
            scr0[hh] = 64.f / l0;
            scr1[hh] = 64.f / l1;
        }
    }

    f32x4 acc[2][2];
#pragma unroll
    for (int mt = 0; mt < 2; ++mt)
#pragma unroll
        for (int nt = 0; nt < 2; ++nt) acc[mt][nt] = (f32x4){0.f, 0.f, 0.f, 0.f};

    // T14 prologue: tile 0 into regs
    uint4 ra0, ra1, rb0, rb1;
    uint4 rp00, rp01, rp02, rp03, rp10, rp11, rp12, rp13;
    if (MODE == MODE_FIN) {
        rp00 = *(const uint4*)(a0p);
        rp01 = *(const uint4*)(a0p + 2097152);
        rp02 = *(const uint4*)(a0p + 2 * 2097152);
        rp03 = *(const uint4*)(a0p + 3 * 2097152);
        rp10 = *(const uint4*)(a1p);
        rp11 = *(const uint4*)(a1p + 2097152);
        rp12 = *(const uint4*)(a1p + 2 * 2097152);
        rp13 = *(const uint4*)(a1p + 3 * 2097152);
    } else {
        ra0 = *(const uint4*)a0p;
        ra1 = *(const uint4*)a1p;
    }
    rb0 = *(const uint4*)b0p;
    rb1 = *(const uint4*)b1p;

#pragma unroll
    for (int kt = 0; kt < DM; kt += 64) {
        const int h = kt >> 6;
        // write staged regs to LDS (prev compute done at loop-end barrier)
        if (MODE == MODE_FIN) {
            union { uint4 u; __half2 h2[4]; } u0, u1, u2, u3;
            float f[8];
            u0.u = rp00; u1.u = rp01; u2.u = rp02; u3.u = rp03;
#pragma unroll
            for (int j = 0; j < 4; ++j) {
                __half2 s2 = __hadd2(__hadd2(u0.h2[j], u1.h2[j]),
                                     __hadd2(u2.h2[j], u3.h2[j]));
                float2 fl = __half22float2(s2);
                f[2 * j]     = fl.x * scr0[h];
                f[2 * j + 1] = fl.y * scr0[h];
            }
            *(uint4*)&As[sr * 72 + scl] = pack8bf(f);
            u0.u = rp10; u1.u = rp11; u2.u = rp12; u3.u = rp13;
#pragma unroll
            for (int j = 0; j < 4; ++j) {
                __half2 s2 = __hadd2(__hadd2(u0.h2[j], u1.h2[j]),
                                     __hadd2(u2.h2[j], u3.h2[j]));
                float2 fl = __half22float2(s2);
                f[2 * j]     = fl.x * scr1[h];
                f[2 * j + 1] = fl.y * scr1[h];
            }
            *(uint4*)&As[(sr + 32) * 72 + scl] = pack8bf(f);
        } else {
            *(uint4*)&As[sr * 72 + scl]        = ra0;
            *(uint4*)&As[(sr + 32) * 72 + scl] = ra1;
        }
        *(uint4*)&Bs[sr * 72 + scl]        = rb0;
        *(uint4*)&Bs[(sr + 32) * 72 + scl] = rb1;
        __syncthreads();

        // issue next tile's global loads — complete under the MFMAs
        if (kt + 64 < DM) {
            if (MODE == MODE_FIN) {
                rp00 = *(const uint4*)(a0p + kt + 64);
                rp01 = *(const uint4*)(a0p + kt + 64 + 2097152);
                rp02 = *(const uint4*)(a0p + kt + 64 + 2 * 2097152);
                rp03 = *(const uint4*)(a0p + kt + 64 + 3 * 2097152);
                rp10 = *(const uint4*)(a1p + kt + 64);
                rp11 = *(const uint4*)(a1p + kt + 64 + 2097152);
                rp12 = *(const uint4*)(a1p + kt + 64 + 2 * 2097152);
                rp13 = *(const uint4*)(a1p + kt + 64 + 3 * 2097152);
            } else {
                ra0 = *(const uint4*)(a0p + kt + 64);
                ra1 = *(const uint4*)(a1p + kt + 64);
            }
            rb0 = *(const uint4*)(b0p + kt + 64);
            rb1 = *(const uint4*)(b1p + kt + 64);
        }

#pragma unroll
        for (int ks = 0; ks < 2; ++ks) {
            bf16x8 af[2], bfr[2];
#pragma unroll
            for (int mt = 0; mt < 2; ++mt)
                af[mt] = ld_bf8(&As[(wm + mt * 16 + ln15) * 72 + ks * 32 + quad * 8]);
#pragma unroll
            for (int nt = 0; nt < 2; ++nt)
                bfr[nt] = ld_bf8(&Bs[(wn + nt * 16 + ln15) * 72 + ks * 32 + quad * 8]);
#pragma unroll
            for (int mt = 0; mt < 2; ++mt)
#pragma unroll
                for (int nt = 0; nt < 2; ++nt)
                    acc[mt][nt] = __builtin_amdgcn_mfma_f32_16x16x32_bf16(
                        af[mt], bfr[nt], acc[mt][nt], 0, 0, 0);
        }
        __syncthreads();
    }

    float bc[2];
#pragma unroll
    for (int nt = 0; nt < 2; ++nt) bc[nt] = bias[col0 + wn + nt * 16 + ln15];
    const int h = col0 >> 6;   // BN=64 == one head

    if (MODE == MODE_FIN) {
        float* outF = (float*)outv;
#pragma unroll
        for (int mt = 0; mt < 2; ++mt)
#pragma unroll
            for (int r = 0; r < 4; ++r) {
                int m = row0 + wm + mt * 16 + quad * 4 + r;
#pragma unroll
                for (int nt = 0; nt < 2; ++nt)
                    outF[(size_t)m * DM + col0 + wn + nt * 16 + ln15] = acc[mt][nt][r] + bc[nt];
            }
    } else if (MODE == MODE_QK) {
        u16* outB = (u16*)outv;
#pragma unroll
        for (int mt = 0; mt < 2; ++mt)
#pragma unroll
            for (int r = 0; r < 4; ++r) {
                int m = row0 + wm + mt * 16 + quad * 4 + r;
                int b = m >> 11, s2 = m & (SEQ - 1);
#pragma unroll
                for (int nt = 0; nt < 2; ++nt) {
                    int dk = wn + nt * 16 + ln15;
                    outB[((size_t)((b * NUM_H + h) * SEQ + s2)) * DK + dk] =
                        f2bf(acc[mt][nt][r] + bc[nt]);
                }
            }
    } else {   // MODE_VT: out [b][h][dk][s]; LDS transpose (reuse As, 64x72)
        u16* outB = (u16*)outv;
        __syncthreads();   // all frag reads done before As reuse
#pragma unroll
        for (int mt = 0; mt < 2; ++mt)
#pragma unroll
            for (int nt = 0; nt < 2; ++nt) {
                int dk = wn + nt * 16 + ln15;
#pragma unroll
                for (int r = 0; r < 4; ++r) {
                    int sl = wm + mt * 16 + quad * 4 + r;
                    As[dk * 72 + sl] = f2bf(acc[mt][nt][r] + bc[nt]);
                }
            }
        __syncthreads();
        int dk = tid >> 2, ch = (tid & 3) * 16;
        int b = row0 >> 11, s0 = row0 & (SEQ - 1);
        size_t base = ((size_t)((b * NUM_H + h) * DK + dk)) * SEQ + s0 + ch;
        *(uint4*)&outB[base]     = *(const uint4*)&As[dk * 72 + ch];
        *(uint4*)&outB[base + 8] = *(const uint4*)&As[dk * 72 + ch + 8];
    }
}

// Fused QKV: grid (64, 8, 3). Inputs bf16 (pre-converted by convAll).
__global__ __launch_bounds__(256) void qkv_mfma(
    const u16* __restrict__ Xb, const u16* __restrict__ Wscr,
    const float* __restrict__ b0, const float* __restrict__ b1,
    const float* __restrict__ b2,
    u16* __restrict__ oQ, u16* __restrict__ oK, u16* __restrict__ oVt)
{
    __shared__ u16 As[64 * 72];
    __shared__ u16 Bs[64 * 72];
    const int row0 = blockIdx.x * 64, col0 = blockIdx.y * 64;
    const int z = blockIdx.z;
    const u16* X = Xb + (size_t)z * 2097152;
    const u16* W = Wscr + (size_t)z * 262144;
    if (z == 2)
        gemm_core<MODE_VT>(X, W, b2, nullptr, oVt, As, Bs, row0, col0);
    else if (z == 0)
        gemm_core<MODE_QK>(X, W, b0, nullptr, oQ, As, Bs, row0, col0);
    else
        gemm_core<MODE_QK>(X, W, b1, nullptr, oK, As, Bs, row0, col0);
}

// Final projection with fused combine (reads NZ O-partials + l sums).
__global__ __launch_bounds__(256) void final_mfma(
    const u16* __restrict__ Pd, const u16* __restrict__ Wbf,
    const float* __restrict__ Cl, const float* __restrict__ bias,
    float* __restrict__ out)
{
    __shared__ u16 As[64 * 72];
    __shared__ u16 Bs[64 * 72];
    gemm_core<MODE_FIN>(Pd, Wbf, bias, Cl, out, As, Bs,
                        blockIdx.x * 64, blockIdx.y * 64);
}

// ---------------- MFMA flash attention, split-K4, diagonal mask ----------------
// r13: swapped QK^T (P lane-local, no P LDS round-trip).
// r14: T14 async-stage, exp2 folded consts, l via ones-MFMA, uniform diag
//      guard, setprio around PV.
// r15: split-K4 — grid (32,16,4) = 2048 blocks = 8 blocks/CU.
#define LSTR 72
// exp(z*0.125 - 4) == exp2(z*0.125*log2e - 4*log2e)
#define SCL2  0.18033688f
#define BIA2 -5.7708020f
__global__ __launch_bounds__(256) void attn_mfma(
    const u16* __restrict__ Qg, const u16* __restrict__ Kg,
    const u16* __restrict__ Vtg, u16* __restrict__ Pd, float* __restrict__ Cl)
{
    __shared__ u16 Klds[64 * LSTR];
    __shared__ u16 Vtlds[64 * LSTR];

    const int tid = threadIdx.x;
    const int lane = tid & 63;
    const int w = tid >> 6;
    const int ln15 = lane & 15;
    const int quad = lane >> 4;
    const int bh = blockIdx.y;
    const int b = bh >> 3, h = bh & 7;
    const int qb = blockIdx.x * 64;
    const int z = blockIdx.z;
    const int k0 = z * (SEQ / NZ), k1 = k0 + SEQ / NZ;

    const u16* Qp = Qg + (size_t)bh * SEQ * DK;
    const u16* Kp = Kg + (size_t)bh * SEQ * DK;
    const u16* Vp = Vtg + (size_t)bh * DK * SEQ;   // [d][s]

    const int myq = w * 16 + ln15;                 // local q row (0..63)
    const int qrow = qb + myq;
    const bf16x8 qa0 = ld_bf8(&Qp[(size_t)qrow * DK + quad * 8]);
    const bf16x8 qa1 = ld_bf8(&Qp[(size_t)qrow * DK + 32 + quad * 8]);

    // diag-mask lane constants: k == myq hits nt2 == w, quad == myq>>2 (mod 16),
    // element r == ln15 & 3.
    const bool mrow = (quad == (ln15 >> 2));
    const int  mr   = ln15 & 3;

    const s16x4 onesb = (s16x4){(short)0x3F80, (short)0x3F80,
                                (short)0x3F80, (short)0x3F80};

    f32x4 O[4];
    f32x4 Lacc = (f32x4){0.f, 0.f, 0.f, 0.f};
#pragma unroll
    for (int nt = 0; nt < 4; ++nt) O[nt] = (f32x4){0.f, 0.f, 0.f, 0.f};

    const int sr = tid >> 3;
    const int scl = (tid & 7) * 8;
    const u16* kp0 = &Kp[(size_t)sr * DK + scl];
    const u16* kp1 = &Kp[(size_t)(sr + 32) * DK + scl];
    const u16* vp0 = &Vp[(size_t)sr * SEQ + scl];
    const u16* vp1 = &Vp[(size_t)(sr + 32) * SEQ + scl];

    // T14 prologue: first tile into regs
    uint4 kreg0 = *(const uint4*)&kp0[(size_t)k0 * DK];
    uint4 kreg1 = *(const uint4*)&kp1[(size_t)k0 * DK];
    uint4 vreg0 = *(const uint4*)&vp0[k0];
    uint4 vreg1 = *(const uint4*)&vp1[k0];

    for (int kt = k0; kt < k1; kt += 64) {
        // write staged regs to LDS (prev compute finished at loop-end barrier)
        *(uint4*)&Klds[sr * LSTR + scl]         = kreg0;
        *(uint4*)&Klds[(sr + 32) * LSTR + scl]  = kreg1;
        *(uint4*)&Vtlds[sr * LSTR + scl]        = vreg0;
        *(uint4*)&Vtlds[(sr + 32) * LSTR + scl] = vreg1;
        __syncthreads();

        // issue next tile's global loads — they complete under compute
        if (kt + 64 < k1) {
            kreg0 = *(const uint4*)&kp0[(size_t)(kt + 64) * DK];
            kreg1 = *(const uint4*)&kp1[(size_t)(kt + 64) * DK];
            vreg0 = *(const uint4*)&vp0[kt + 64];
            vreg1 = *(const uint4*)&vp1[kt + 64];
        }

        const bool diagt = (kt == qb);
        // swapped QK^T: per nt2 lane gets S[q=myq][k = nt2*16 + quad*4 + r]
        s16x4 pa[4];
#pragma unroll
        for (int nt2 = 0; nt2 < 4; ++nt2) {
            bf16x8 kb0 = ld_bf8(&Klds[(nt2 * 16 + ln15) * LSTR + quad * 8]);
            bf16x8 kb1 = ld_bf8(&Klds[(nt2 * 16 + ln15) * LSTR + 32 + quad * 8]);
            f32x4 zacc = (f32x4){0.f, 0.f, 0.f, 0.f};
            zacc = __builtin_amdgcn_mfma_f32_16x16x32_bf16(kb0, qa0, zacc, 0, 0, 0);
            zacc = __builtin_amdgcn_mfma_f32_16x16x32_bf16(kb1, qa1, zacc, 0, 0, 0);
            union { u16 u[4]; s16x4 v; } pk;
#pragma unroll
            for (int r = 0; r < 4; ++r)
                pk.u[r] = f2bf(fexp2(fmaf(zacc[r], SCL2, BIA2)));
            if (diagt && nt2 == w) {   // wave-uniform guard; 1/16 tiles, 1/4 nt2
#pragma unroll
                for (int r = 0; r < 4; ++r)
                    if (mrow && r == mr) pk.u[r] = 0;
            }
            pa[nt2] = pk.v;
        }

        // PV via K=16 MFMA: A = in-register P fragments, B = V^T b64 reads.
        // Extra ones-column accumulates the row sum l on the matrix pipe.
        const u16* vb_base = &Vtlds[ln15 * LSTR + quad * 4];
        __builtin_amdgcn_s_setprio(1);
#pragma unroll
        for (int nt2 = 0; nt2 < 4; ++nt2)
            Lacc = mfma16bf(pa[nt2], onesb, Lacc);
#pragma unroll
        for (int nt = 0; nt < 4; ++nt) {
#pragma unroll
            for (int nt2 = 0; nt2 < 4; ++nt2) {
                s16x4 vb = *(const s16x4*)&vb_base[nt * 16 * LSTR + nt2 * 16];
                O[nt] = mfma16bf(pa[nt2], vb, O[nt]);
            }
        }
        __builtin_amdgcn_s_setprio(0);
        __syncthreads();
    }

    // Lacc[r] = l for q = qb + w*16 + quad*4 + r (same value across ln15)
    if (ln15 == 0) {
#pragma unroll
        for (int r = 0; r < 4; ++r)
            Cl[(size_t)z * 32768 + bh * SEQ + qb + w * 16 + quad * 4 + r] = Lacc[r];
    }

    // write unnormalized O partial (fp16, scaled 1/64)
#pragma unroll
    for (int r = 0; r < 4; ++r) {
        int s = qb + w * 16 + quad * 4 + r;
        size_t base = (size_t)z * 2097152 + ((size_t)(b * SEQ + s)) * DM + h * DK;
#pragma unroll
        for (int nt = 0; nt < 4; ++nt)
            Pd[base + nt * 16 + ln15] = f2h(O[nt][r] * 0.015625f);
    }
}

extern "C" void kernel_launch(void* const* d_in, const int* in_sizes, int n_in,
                              void* d_out, int out_size, void* d_ws, size_t ws_size,
                              hipStream_t stream) {
    const float* q  = (const float*)d_in[0];
    const float* k  = (const float*)d_in[1];
    const float* v  = (const float*)d_in[2];
    const float* Wq = (const float*)d_in[3];
    const float* bq = (const float*)d_in[4];
    const float* Wk = (const float*)d_in[5];
    const float* bk = (const float*)d_in[6];
    const float* Wv = (const float*)d_in[7];
    const float* bv = (const float*)d_in[8];
    const float* Wo = (const float*)d_in[9];
    const float* bo = (const float*)d_in[10];
    float* out = (float*)d_out;

    // ws layout (~42.5 MB of the 256 MB arena):
    //   Qb, Kb, Vtb   bf16 [4096][512]        4 MB each
    //   Cl            fp32 [NZ][16][2048]     512 KB
    //   Wscr          bf16 Wq,Wk,Wv,Wo        2 MB
    //   Pd            fp16 [NZ][4096][512]    16 MB (attn O-partials)
    //   Xb            bf16 [3][4096][512]     12 MB (converted q,k,v)
    const size_t TSZ = (size_t)MROWS * DM;   // 2,097,152
    u16* Qb   = (u16*)d_ws;
    u16* Kb   = Qb + TSZ;
    u16* Vtb  = Qb + 2 * TSZ;
    float* Cl = (float*)(Qb + 3 * TSZ);      // NZ*32768 = 131072 floats
    u16* Wscr = (u16*)(Cl + 131072);         // 4*262144 u16
    u16* Pd   = Wscr + 4 * 262144;           // NZ*TSZ u16
    u16* Xb   = Pd + (size_t)NZ * TSZ;       // 3*TSZ u16

    dim3 blk(256);
    hipLaunchKernelGGL(convAll, dim3(1024, 7), blk, 0, stream,
                       Wq, Wk, Wv, Wo, q, k, v, Wscr, Xb);
    dim3 gq(MROWS / 64, DM / 64, 3);         // (64, 8, 3) = 1536 blocks, 6/CU
    hipLaunchKernelGGL(qkv_mfma, gq, blk, 0, stream,
                       Xb, Wscr, bq, bk, bv, Qb, Kb, Vtb);
    dim3 ga(SEQ / 64, NB * NUM_H, NZ);       // (32, 16, 4) = 2048 blocks, 8/CU
    hipLaunchKernelGGL(attn_mfma, ga, blk, 0, stream, Qb, Kb, Vtb, Pd, Cl);
    dim3 gf(MROWS / 64, DM / 64);            // (64, 8) = 512 blocks, 2/CU
    hipLaunchKernelGGL(final_mfma, gf, blk, 0, stream, Pd, Wscr + 3 * 262144, Cl, bo, out);
}

// Round 5
// 146.897 us; speedup vs baseline: 1.0508x; 1.0508x over previous
//
#include <hip/hip_runtime.h>
#include <hip/hip_bf16.h>
#include <hip/hip_fp16.h>
#include <math.h>

#define NUM_H 8
#define DK    64
#define DM    512
#define SEQ   2048
#define NB    2
#define MROWS (NB*SEQ)   // 4096
#define NZ    4          // attn split-K factor

typedef unsigned short u16;
typedef unsigned int   u32;
typedef __attribute__((ext_vector_type(8))) __bf16 bf16x8;
typedef __attribute__((ext_vector_type(4))) short  s16x4;
typedef __attribute__((ext_vector_type(4))) float  f32x4;

// Native RNE cast (compiler emits v_cvt_pk_bf16_f32 for pairs).
__device__ __forceinline__ u16 f2bf(float v) {
    union { __bf16 h; u16 u; } x; x.h = (__bf16)v; return x.u;
}
__device__ __forceinline__ u16 f2h(float v) {
    union { _Float16 h; u16 u; } x; x.h = (_Float16)v; return x.u;
}
__device__ __forceinline__ bf16x8 ld_bf8(const u16* p) {
    union { uint4 u; bf16x8 v; } t;
    t.u = *(const uint4*)p;
    return t.v;
}
__device__ __forceinline__ uint4 pack8bf(const float* f) {
    uint4 o;
    o.x = (u32)f2bf(f[0]) | ((u32)f2bf(f[1]) << 16);
    o.y = (u32)f2bf(f[2]) | ((u32)f2bf(f[3]) << 16);
    o.z = (u32)f2bf(f[4]) | ((u32)f2bf(f[5]) << 16);
    o.w = (u32)f2bf(f[6]) | ((u32)f2bf(f[7]) << 16);
    return o;
}
// exp2 that maps straight to v_exp_f32 (no hidden *log2e mul).
__device__ __forceinline__ float fexp2(float x) {
#if defined(__has_builtin) && __has_builtin(__builtin_amdgcn_exp2f)
    return __builtin_amdgcn_exp2f(x);
#else
    return exp2f(x);
#endif
}

// K=16 bf16 MFMA (A/B: 4 bf16 in 2 VGPR). Used for PV so the swapped-QK^T
// score layout (lane holds k = nt2*16 + quad*4 + r) feeds MFMA A directly.
__device__ __forceinline__ f32x4 mfma16bf(s16x4 a, s16x4 b, f32x4 c) {
#if defined(__has_builtin) && __has_builtin(__builtin_amdgcn_mfma_f32_16x16x16bf16_1k)
    return __builtin_amdgcn_mfma_f32_16x16x16bf16_1k(a, b, c, 0, 0, 0);
#else
    asm("v_mfma_f32_16x16x16_bf16 %0, %1, %2, %0" : "+v"(c) : "v"(a), "v"(b));
    return c;
#endif
}

// Convert Wq,Wk,Wv,Wo (fp32 512x512) -> bf16 into Wscr. grid (128,4) x 256.
// (r17: convAll reverted — the extra full pass over q,k,v cost ~9 us and was
// never paid back; qkv's in-loop conversion was already latency-hidden.)
__global__ __launch_bounds__(256) void convW(
    const float* __restrict__ Wq, const float* __restrict__ Wk,
    const float* __restrict__ Wv, const float* __restrict__ Wo,
    u16* __restrict__ Wscr)
{
    const int z = blockIdx.y;
    const float* src = (z == 0) ? Wq : (z == 1) ? Wk : (z == 2) ? Wv : Wo;
    u16* dst = Wscr + (size_t)z * 262144;
    int i = (blockIdx.x * 256 + threadIdx.x) * 8;
    float4 a = *(const float4*)(src + i);
    float4 b = *(const float4*)(src + i + 4);
    float f[8] = {a.x, a.y, a.z, a.w, b.x, b.y, b.z, b.w};
    *(uint4*)&dst[i] = pack8bf(f);
}

// ---------------- MFMA GEMM core: OUT = X @ W^T + bias (W bf16) ----------------
// r15-proven structure (149.9us total): BM=BN=BK=64, 256 thr / 4 waves,
// LDS stride 72 u16, single-buffer 2-barrier K-loop, fp32 A staged with
// in-loop bf16 pack. MODE_FIN fuses combine (NZ fp16 partial sum + 64/l).
#define MODE_QK 0
#define MODE_VT 1
#define MODE_FIN 2

template<int MODE>
__device__ __forceinline__ void gemm_core(
    const void* __restrict__ Xv, const u16* __restrict__ Wb,
    const float* __restrict__ bias, const float* __restrict__ ClP,
    void* __restrict__ outv,
    u16* As, u16* Bs, int row0, int col0)
{
    const int tid = threadIdx.x;
    const int lane = tid & 63, w = tid >> 6;
    const int ln15 = lane & 15, quad = lane >> 4;
    const int wm = (w >> 1) * 32, wn = (w & 1) * 32;

    // CMB row constants: each thread stages rows r0=tid/8 and r0+32 every iter.
    int cb0 = 0, cs0 = 0, cb1 = 0, cs1 = 0;
    if (MODE == MODE_FIN) {
        int m0 = row0 + (tid >> 3), m1 = m0 + 32;
        cb0 = (m0 >> 11) * NUM_H; cs0 = m0 & (SEQ - 1);
        cb1 = (m1 >> 11) * NUM_H; cs1 = m1 & (SEQ - 1);
    }

    f32x4 acc[2][2];
#pragma unroll
    for (int mt = 0; mt < 2; ++mt)
#pragma unroll
        for (int nt = 0; nt < 2; ++nt) acc[mt][nt] = (f32x4){0.f, 0.f, 0.f, 0.f};

    for (int kt = 0; kt < DM; kt += 64) {
        __syncthreads();
        if (MODE == MODE_FIN) {
            // fused combine stage: A[r][c] = (sum_z Pd[z][m][kt+c]) * 64/l(m,h)
            const int h = kt >> 6;   // col block == one head
            float l0 = ClP[(cb0 + h) * SEQ + cs0] + ClP[32768 + (cb0 + h) * SEQ + cs0]
                     + ClP[65536 + (cb0 + h) * SEQ + cs0] + ClP[98304 + (cb0 + h) * SEQ + cs0];
            float l1 = ClP[(cb1 + h) * SEQ + cs1] + ClP[32768 + (cb1 + h) * SEQ + cs1]
                     + ClP[65536 + (cb1 + h) * SEQ + cs1] + ClP[98304 + (cb1 + h) * SEQ + cs1];
            float scr[2] = {64.f / l0, 64.f / l1};
#pragma unroll
            for (int g = 0; g < 2; ++g) {
                int r = g * 32 + (tid >> 3);
                int c = (tid & 7) * 8;
                const u16* pp = (const u16*)Xv + (size_t)(row0 + r) * DM + kt + c;
                union { uint4 u; __half2 h2[4]; } u0, u1, u2, u3;
                u0.u = *(const uint4*)pp;
                u1.u = *(const uint4*)(pp + 2097152);
                u2.u = *(const uint4*)(pp + 2 * 2097152);
                u3.u = *(const uint4*)(pp + 3 * 2097152);
                float f[8];
                float sc = scr[g];
#pragma unroll
                for (int j = 0; j < 4; ++j) {
                    __half2 s2 = __hadd2(__hadd2(u0.h2[j], u1.h2[j]),
                                         __hadd2(u2.h2[j], u3.h2[j]));
                    float2 fl = __half22float2(s2);
                    f[2 * j]     = fl.x * sc;
                    f[2 * j + 1] = fl.y * sc;
                }
                *(uint4*)&As[r * 72 + c] = pack8bf(f);
            }
        } else {
            // stage A: 64x64 from fp32 input (bf16-packed on the fly)
#pragma unroll
            for (int g = 0; g < 2; ++g) {
                int idx = g * 2048 + tid * 8;
                int r = idx >> 6, c = idx & 63;
                const float* xp = (const float*)Xv + (size_t)(row0 + r) * DM + kt + c;
                float4 a = *(const float4*)xp;
                float4 b2 = *(const float4*)(xp + 4);
                float f[8] = {a.x, a.y, a.z, a.w, b2.x, b2.y, b2.z, b2.w};
                *(uint4*)&As[r * 72 + c] = pack8bf(f);
            }
        }
        // stage B: 64x64, W bf16 layout [n][k]
#pragma unroll
        for (int g = 0; g < 2; ++g) {
            int idx = g * 2048 + tid * 8;
            int r = idx >> 6, c = idx & 63;
            *(uint4*)&Bs[r * 72 + c] =
                *(const uint4*)(Wb + (size_t)(col0 + r) * DM + kt + c);
        }
        __syncthreads();

#pragma unroll
        for (int ks = 0; ks < 2; ++ks) {
            bf16x8 af[2], bfr[2];
#pragma unroll
            for (int mt = 0; mt < 2; ++mt)
                af[mt] = ld_bf8(&As[(wm + mt * 16 + ln15) * 72 + ks * 32 + quad * 8]);
#pragma unroll
            for (int nt = 0; nt < 2; ++nt)
                bfr[nt] = ld_bf8(&Bs[(wn + nt * 16 + ln15) * 72 + ks * 32 + quad * 8]);
#pragma unroll
            for (int mt = 0; mt < 2; ++mt)
#pragma unroll
                for (int nt = 0; nt < 2; ++nt)
                    acc[mt][nt] = __builtin_amdgcn_mfma_f32_16x16x32_bf16(
                        af[mt], bfr[nt], acc[mt][nt], 0, 0, 0);
        }
    }

    float bc[2];
#pragma unroll
    for (int nt = 0; nt < 2; ++nt) bc[nt] = bias[col0 + wn + nt * 16 + ln15];
    const int h = col0 >> 6;   // BN=64 == one head

    if (MODE == MODE_FIN) {
        float* outF = (float*)outv;
#pragma unroll
        for (int mt = 0; mt < 2; ++mt)
#pragma unroll
            for (int r = 0; r < 4; ++r) {
                int m = row0 + wm + mt * 16 + quad * 4 + r;
#pragma unroll
                for (int nt = 0; nt < 2; ++nt)
                    outF[(size_t)m * DM + col0 + wn + nt * 16 + ln15] = acc[mt][nt][r] + bc[nt];
            }
    } else if (MODE == MODE_QK) {
        u16* outB = (u16*)outv;
#pragma unroll
        for (int mt = 0; mt < 2; ++mt)
#pragma unroll
            for (int r = 0; r < 4; ++r) {
                int m = row0 + wm + mt * 16 + quad * 4 + r;
                int b = m >> 11, s2 = m & (SEQ - 1);
#pragma unroll
                for (int nt = 0; nt < 2; ++nt) {
                    int dk = wn + nt * 16 + ln15;
                    outB[((size_t)((b * NUM_H + h) * SEQ + s2)) * DK + dk] =
                        f2bf(acc[mt][nt][r] + bc[nt]);
                }
            }
    } else {   // MODE_VT: out [b][h][dk][s]; LDS transpose (reuse As, 64x72)
        u16* outB = (u16*)outv;
        __syncthreads();   // all frag reads done before As reuse
#pragma unroll
        for (int mt = 0; mt < 2; ++mt)
#pragma unroll
            for (int nt = 0; nt < 2; ++nt) {
                int dk = wn + nt * 16 + ln15;
#pragma unroll
                for (int r = 0; r < 4; ++r) {
                    int sl = wm + mt * 16 + quad * 4 + r;
                    As[dk * 72 + sl] = f2bf(acc[mt][nt][r] + bc[nt]);
                }
            }
        __syncthreads();
        int dk = tid >> 2, ch = (tid & 3) * 16;
        int b = row0 >> 11, s0 = row0 & (SEQ - 1);
        size_t base = ((size_t)((b * NUM_H + h) * DK + dk)) * SEQ + s0 + ch;
        *(uint4*)&outB[base]     = *(const uint4*)&As[dk * 72 + ch];
        *(uint4*)&outB[base + 8] = *(const uint4*)&As[dk * 72 + ch + 8];
    }
}

// Fused QKV: grid (64, 8, 3). Inputs fp32 (bf16-packed during staging).
__global__ __launch_bounds__(256) void qkv_mfma(
    const float* __restrict__ xq, const float* __restrict__ xk, const float* __restrict__ xv,
    const u16* __restrict__ Wscr,
    const float* __restrict__ b0, const float* __restrict__ b1, const float* __restrict__ b2,
    u16* __restrict__ oQ, u16* __restrict__ oK, u16* __restrict__ oVt)
{
    __shared__ u16 As[64 * 72];
    __shared__ u16 Bs[64 * 72];
    const int row0 = blockIdx.x * 64, col0 = blockIdx.y * 64;
    const int z = blockIdx.z;
    const u16* W = Wscr + (size_t)z * 262144;
    if (z == 2)
        gemm_core<MODE_VT>(xv, W, b2, nullptr, oVt, As, Bs, row0, col0);
    else if (z == 0)
        gemm_core<MODE_QK>(xq, W, b0, nullptr, oQ, As, Bs, row0, col0);
    else
        gemm_core<MODE_QK>(xk, W, b1, nullptr, oK, As, Bs, row0, col0);
}

// Final projection with fused combine (reads NZ O-partials + l sums).
__global__ __launch_bounds__(256) void final_mfma(
    const u16* __restrict__ Pd, const u16* __restrict__ Wbf,
    const float* __restrict__ Cl, const float* __restrict__ bias,
    float* __restrict__ out)
{
    __shared__ u16 As[64 * 72];
    __shared__ u16 Bs[64 * 72];
    gemm_core<MODE_FIN>(Pd, Wbf, bias, Cl, out, As, Bs,
                        blockIdx.x * 64, blockIdx.y * 64);
}

// ---------------- MFMA flash attention, split-K4, diagonal mask ----------------
// r13: swapped QK^T (P lane-local). r14: T14 async-stage, exp2, ones-MFMA l,
// uniform diag guard, setprio. r15: split-K4.
// r17: QBLK=128 — each wave owns TWO 16-row q-sets (32 q rows). Pipe-seconds
// accounting showed LDS is attn's dominant pipe (~16.7us/CU vs matrix 13.3):
// every wave re-reads the full 8KB K-tile and 8KB V-tile as fragments. With
// two q-sets, kb and vb fragments are loaded ONCE and feed both sets' MFMAs
// -> LDS bytes per unit work halve. Grid (NZ, bh, qb) so XCD = (z+4bh)%8 is
// constant across qb -> K/V L2-local per XCD.
#define LSTR 72
// exp(z*0.125 - 4) == exp2(z*0.125*log2e - 4*log2e)
#define SCL2  0.18033688f
#define BIA2 -5.7708020f
__global__ __launch_bounds__(256, 4) void attn_mfma(
    const u16* __restrict__ Qg, const u16* __restrict__ Kg,
    const u16* __restrict__ Vtg, u16* __restrict__ Pd, float* __restrict__ Cl)
{
    __shared__ u16 Klds[64 * LSTR];
    __shared__ u16 Vtlds[64 * LSTR];

    const int tid = threadIdx.x;
    const int lane = tid & 63;
    const int w = tid >> 6;
    const int ln15 = lane & 15;
    const int quad = lane >> 4;
    const int bh = blockIdx.y;
    const int b = bh >> 3, h = bh & 7;
    const int qb = blockIdx.z * 128;      // 16 q-blocks of 128 rows
    const int z = blockIdx.x;             // NZ split-K slabs
    const int k0 = z * (SEQ / NZ), k1 = k0 + SEQ / NZ;

    const u16* Qp = Qg + (size_t)bh * SEQ * DK;
    const u16* Kp = Kg + (size_t)bh * SEQ * DK;
    const u16* Vp = Vtg + (size_t)bh * DK * SEQ;   // [d][s]

    // two q-sets per wave: q = qb + w*32 + s*16 + ln15
    const int myq0 = w * 32 + ln15;
    bf16x8 qa[2][2];
    qa[0][0] = ld_bf8(&Qp[(size_t)(qb + myq0) * DK + quad * 8]);
    qa[0][1] = ld_bf8(&Qp[(size_t)(qb + myq0) * DK + 32 + quad * 8]);
    qa[1][0] = ld_bf8(&Qp[(size_t)(qb + myq0 + 16) * DK + quad * 8]);
    qa[1][1] = ld_bf8(&Qp[(size_t)(qb + myq0 + 16) * DK + 32 + quad * 8]);

    // diag-mask lane constants: within the wave's diagonal k-tile
    // (kt == qb + (w>>1)*64), set s hits nt2 == (w&1)*2 + s, lane element
    // (quad == ln15>>2, r == ln15&3).
    const bool mrow = (quad == (ln15 >> 2));
    const int  mr   = ln15 & 3;
    const int  diag_kt = qb + (w >> 1) * 64;
    const int  nt2d = (w & 1) * 2;

    const s16x4 onesb = (s16x4){(short)0x3F80, (short)0x3F80,
                                (short)0x3F80, (short)0x3F80};

    f32x4 O[2][4];
    f32x4 Lacc[2];
#pragma unroll
    for (int s = 0; s < 2; ++s) {
        Lacc[s] = (f32x4){0.f, 0.f, 0.f, 0.f};
#pragma unroll
        for (int nt = 0; nt < 4; ++nt) O[s][nt] = (f32x4){0.f, 0.f, 0.f, 0.f};
    }

    const int sr = tid >> 3;
    const int scl = (tid & 7) * 8;
    const u16* kp0 = &Kp[(size_t)sr * DK + scl];
    const u16* kp1 = &Kp[(size_t)(sr + 32) * DK + scl];
    const u16* vp0 = &Vp[(size_t)sr * SEQ + scl];
    const u16* vp1 = &Vp[(size_t)(sr + 32) * SEQ + scl];

    // T14 prologue: first tile into regs
    uint4 kreg0 = *(const uint4*)&kp0[(size_t)k0 * DK];
    uint4 kreg1 = *(const uint4*)&kp1[(size_t)k0 * DK];
    uint4 vreg0 = *(const uint4*)&vp0[k0];
    uint4 vreg1 = *(const uint4*)&vp1[k0];

    for (int kt = k0; kt < k1; kt += 64) {
        // write staged regs to LDS (prev compute finished at loop-end barrier)
        *(uint4*)&Klds[sr * LSTR + scl]         = kreg0;
        *(uint4*)&Klds[(sr + 32) * LSTR + scl]  = kreg1;
        *(uint4*)&Vtlds[sr * LSTR + scl]        = vreg0;
        *(uint4*)&Vtlds[(sr + 32) * LSTR + scl] = vreg1;
        __syncthreads();

        // issue next tile's global loads — they complete under compute
        if (kt + 64 < k1) {
            kreg0 = *(const uint4*)&kp0[(size_t)(kt + 64) * DK];
            kreg1 = *(const uint4*)&kp1[(size_t)(kt + 64) * DK];
            vreg0 = *(const uint4*)&vp0[kt + 64];
            vreg1 = *(const uint4*)&vp1[kt + 64];
        }

        const bool diagt = (kt == diag_kt);
        // swapped QK^T: kb fragments loaded once, feed BOTH q-sets.
        s16x4 pa[2][4];
#pragma unroll
        for (int nt2 = 0; nt2 < 4; ++nt2) {
            bf16x8 kb0 = ld_bf8(&Klds[(nt2 * 16 + ln15) * LSTR + quad * 8]);
            bf16x8 kb1 = ld_bf8(&Klds[(nt2 * 16 + ln15) * LSTR + 32 + quad * 8]);
#pragma unroll
            for (int s = 0; s < 2; ++s) {
                f32x4 zacc = (f32x4){0.f, 0.f, 0.f, 0.f};
                zacc = __builtin_amdgcn_mfma_f32_16x16x32_bf16(kb0, qa[s][0], zacc, 0, 0, 0);
                zacc = __builtin_amdgcn_mfma_f32_16x16x32_bf16(kb1, qa[s][1], zacc, 0, 0, 0);
                union { u16 u[4]; s16x4 v; } pk;
#pragma unroll
                for (int r = 0; r < 4; ++r)
                    pk.u[r] = f2bf(fexp2(fmaf(zacc[r], SCL2, BIA2)));
                if (diagt && nt2 == nt2d + s) {   // wave-uniform guard
#pragma unroll
                    for (int r = 0; r < 4; ++r)
                        if (mrow && r == mr) pk.u[r] = 0;
                }
                pa[s][nt2] = pk.v;
            }
        }

        // PV via K=16 MFMA: vb fragments loaded once, feed BOTH q-sets.
        const u16* vb_base = &Vtlds[ln15 * LSTR + quad * 4];
        __builtin_amdgcn_s_setprio(1);
#pragma unroll
        for (int nt2 = 0; nt2 < 4; ++nt2) {
            Lacc[0] = mfma16bf(pa[0][nt2], onesb, Lacc[0]);
            Lacc[1] = mfma16bf(pa[1][nt2], onesb, Lacc[1]);
        }
#pragma unroll
        for (int nt = 0; nt < 4; ++nt) {
#pragma unroll
            for (int nt2 = 0; nt2 < 4; ++nt2) {
                s16x4 vb = *(const s16x4*)&vb_base[nt * 16 * LSTR + nt2 * 16];
                O[0][nt] = mfma16bf(pa[0][nt2], vb, O[0][nt]);
                O[1][nt] = mfma16bf(pa[1][nt2], vb, O[1][nt]);
            }
        }
        __builtin_amdgcn_s_setprio(0);
        __syncthreads();
    }

    // Lacc[s][r] = l for q = qb + w*32 + s*16 + quad*4 + r (same across ln15)
    if (ln15 == 0) {
#pragma unroll
        for (int s = 0; s < 2; ++s)
#pragma unroll
            for (int r = 0; r < 4; ++r)
                Cl[(size_t)z * 32768 + bh * SEQ + qb + w * 32 + s * 16 + quad * 4 + r]
                    = Lacc[s][r];
    }

    // write unnormalized O partial (fp16, scaled 1/64)
#pragma unroll
    for (int s = 0; s < 2; ++s)
#pragma unroll
        for (int r = 0; r < 4; ++r) {
            int sq = qb + w * 32 + s * 16 + quad * 4 + r;
            size_t base = (size_t)z * 2097152 + ((size_t)(b * SEQ + sq)) * DM + h * DK;
#pragma unroll
            for (int nt = 0; nt < 4; ++nt)
                Pd[base + nt * 16 + ln15] = f2h(O[s][nt][r] * 0.015625f);
        }
}

extern "C" void kernel_launch(void* const* d_in, const int* in_sizes, int n_in,
                              void* d_out, int out_size, void* d_ws, size_t ws_size,
                              hipStream_t stream) {
    const float* q  = (const float*)d_in[0];
    const float* k  = (const float*)d_in[1];
    const float* v  = (const float*)d_in[2];
    const float* Wq = (const float*)d_in[3];
    const float* bq = (const float*)d_in[4];
    const float* Wk = (const float*)d_in[5];
    const float* bk = (const float*)d_in[6];
    const float* Wv = (const float*)d_in[7];
    const float* bv = (const float*)d_in[8];
    const float* Wo = (const float*)d_in[9];
    const float* bo = (const float*)d_in[10];
    float* out = (float*)d_out;

    // ws layout (~30.5 MB of the 256 MB arena):
    //   Qb, Kb, Vtb   bf16 [4096][512]        4 MB each
    //   Cl            fp32 [NZ][16][2048]     512 KB
    //   Wscr          bf16 Wq,Wk,Wv,Wo        2 MB
    //   Pd            fp16 [NZ][4096][512]    16 MB (attn O-partials)
    const size_t TSZ = (size_t)MROWS * DM;   // 2,097,152
    u16* Qb   = (u16*)d_ws;
    u16* Kb   = Qb + TSZ;
    u16* Vtb  = Qb + 2 * TSZ;
    float* Cl = (float*)(Qb + 3 * TSZ);      // NZ*32768 = 131072 floats
    u16* Wscr = (u16*)(Cl + 131072);         // 4*262144 u16
    u16* Pd   = Wscr + 4 * 262144;           // NZ*TSZ u16

    dim3 blk(256);
    hipLaunchKernelGGL(convW, dim3(128, 4), blk, 0, stream, Wq, Wk, Wv, Wo, Wscr);
    dim3 gq(MROWS / 64, DM / 64, 3);         // (64, 8, 3) = 1536 blocks, 6/CU
    hipLaunchKernelGGL(qkv_mfma, gq, blk, 0, stream,
                       q, k, v, Wscr, bq, bk, bv, Qb, Kb, Vtb);
    dim3 ga(NZ, NB * NUM_H, SEQ / 128);      // (4, 16, 16) = 1024 blocks, 4/CU;
                                             // XCD = (z+4bh)%8 const across qb
    hipLaunchKernelGGL(attn_mfma, ga, blk, 0, stream, Qb, Kb, Vtb, Pd, Cl);
    dim3 gf(MROWS / 64, DM / 64);            // (64, 8) = 512 blocks, 2/CU
    hipLaunchKernelGGL(final_mfma, gf, blk, 0, stream, Pd, Wscr + 3 * 262144, Cl, bo, out);
}